// Round 6
// baseline (128.739 us; speedup 1.0000x reference)
//
#include <hip/hip_runtime.h>
#include <stdint.h>

#define KROWS 8192
#define DDIM  768
#define NUMG  256
#define BM    256
#define BK    64
#define NT    (DDIM / BK)                 // 12 K-tiles
#define NTILES (KROWS / BM)               // 32
#define TOTT (NTILES * (NTILES + 1) / 2)  // 528
#define GRID_G 256
#define MARGIN_F 0.1f

typedef short bf16x8 __attribute__((ext_vector_type(8)));
typedef float f32x4 __attribute__((ext_vector_type(4)));
typedef unsigned short u16x8 __attribute__((ext_vector_type(8)));

typedef __attribute__((address_space(3))) unsigned char lds_byte;
typedef __attribute__((address_space(1))) const unsigned char glob_byte;

__device__ __forceinline__ uint32_t enc_f32(float f) {
  uint32_t b = __float_as_uint(f);
  return (b & 0x80000000u) ? ~b : (b | 0x80000000u);
}
__device__ __forceinline__ float dec_f32(uint32_t u) {
  uint32_t b = (u & 0x80000000u) ? (u & 0x7FFFFFFFu) : ~u;
  return __uint_as_float(b);
}
__device__ __forceinline__ unsigned short f2bf(float f) {
  uint32_t b = __float_as_uint(f);
  uint32_t r = (b + 0x7FFFu + ((b >> 16) & 1u)) >> 16;
  return (unsigned short)r;
}

// ------- convert f32->bf16 (8/thread) + gid extract + steal-counter init ----
__global__ void convert_k(const float* __restrict__ x, unsigned short* __restrict__ xb,
                          const int* __restrict__ pidx, int* __restrict__ gids,
                          int* __restrict__ counts, int* __restrict__ ctr) {
  int t = blockIdx.x * blockDim.x + threadIdx.x;
  const float4* p = reinterpret_cast<const float4*>(x + 8 * (size_t)t);
  float4 a = p[0], b = p[1];
  u16x8 r;
  r[0] = f2bf(a.x); r[1] = f2bf(a.y); r[2] = f2bf(a.z); r[3] = f2bf(a.w);
  r[4] = f2bf(b.x); r[5] = f2bf(b.y); r[6] = f2bf(b.z); r[7] = f2bf(b.w);
  *reinterpret_cast<u16x8*>(xb + 8 * (size_t)t) = r;
  if (t < KROWS) {
    int g = pidx[2 * t + 1] & (NUMG - 1);
    gids[t] = g;
    atomicAdd(&counts[g], 1);
  }
  if (t == 0) *ctr = GRID_G;  // stealing starts after the static first round
}

// ---------------- main fused Gram + margin-reduce kernel ----------------
// 256x256 tile, 1024 threads = 16 waves (4x4), per-wave 64x64 (4x4 frags of
// 16x16x32 bf16 MFMA) -> per-thread regs identical to the r1 winner
// (64 AGPR acc + ~64 VGPR -> 4 waves/SIMD, one full 16-wave block/CU).
// Halves L2->LDS staging demand vs 128^2 (405 MB vs 799 MB); r1-style
// serial-drain K-loop; supertile-ordered tile index (4x4-tile supertiles,
// 3 MB working set < 4 MB XCD-L2), XCD-chunked static first round + atomic
// work-stealing for the 272-tile tail (min/max atomics -> order-independent,
// deterministic output).
__launch_bounds__(1024, 4)
__global__ void gram_margin_k(const unsigned short* __restrict__ xb,
                              const int* __restrict__ gids,
                              uint32_t* __restrict__ gmin,
                              uint32_t* __restrict__ gmax,
                              int* __restrict__ ctr) {
  __shared__ unsigned short sA[BM * BK];   // 32 KB
  __shared__ unsigned short sB[BM * BK];   // 32 KB
  __shared__ uint32_t lgmin[NUMG];
  __shared__ uint32_t lgmax[NUMG];
  __shared__ int sgr[BM];
  __shared__ int sgc[BM];
  __shared__ int s_tile;

  const int tid  = threadIdx.x;
  const int lane = tid & 63;
  const int wid  = tid >> 6;            // 0..15
  const int wr   = wid >> 2, wc = wid & 3;
  const int lr   = lane & 15, lh = lane >> 4;
  const int srow = tid >> 3;            // 0..127
  const int schunk = tid & 7;           // 16B chunk in 128B row

  bool first = true;
  for (;;) {
    if (tid == 0) s_tile = first ? (int)blockIdx.x : atomicAdd(ctr, 1);
    __syncthreads();
    first = false;
    const int st = s_tile;
    if (st >= TOTT) break;

    // st -> idx: static round XCD-chunked (66 tiles per XCD), steal tail
    // fills each chunk's remaining 34. idx is supertile-contiguous:
    // idx 0..79 = 8 diagonal 4x4 supertiles (10 tiles each),
    // idx 80..527 = 28 off-diagonal supertiles (16 tiles each).
    int idx;
    if (st < GRID_G) idx = (st & 7) * 66 + (st >> 3);
    else { int e = st - GRID_G; idx = (e & 7) * 66 + 32 + (e >> 3); }

    int ib, jb;
    if (idx < 80) {
      int d = idx / 10, r = idx - d * 10;
      int i2 = 0;
      while ((i2 + 1) * (i2 + 2) / 2 <= r) ++i2;
      int j2 = r - i2 * (i2 + 1) / 2;
      ib = d * 4 + i2; jb = d * 4 + j2;
    } else {
      int e = idx - 80;
      int o = e >> 4, t = e & 15;
      int si = 1;
      while (si * (si + 1) / 2 <= o) ++si;
      int sj = o - si * (si - 1) / 2;
      ib = si * 4 + (t >> 2); jb = sj * 4 + (t & 3);
    }
    const int i0 = ib * BM, j0 = jb * BM;

    if (tid < NUMG) {
      lgmin[tid] = 0xFFFFFFFFu; lgmax[tid] = 0u;
      sgr[tid] = gids[i0 + tid];
      sgc[tid] = gids[j0 + tid];
    }

    f32x4 acc[4][4];
    const f32x4 zz = {0.f, 0.f, 0.f, 0.f};
#pragma unroll
    for (int m = 0; m < 4; ++m)
#pragma unroll
      for (int n = 0; n < 4; ++n) acc[m][n] = zz;

    for (int kt = 0; kt < NT; ++kt) {
      const int k0 = kt * BK;
#pragma unroll
      for (int c = 0; c < 2; ++c) {
        int row = c * 128 + srow;
        int chunk = schunk ^ (row & 7);  // pre-swizzle global source
        const unsigned short* ga = xb + (size_t)(i0 + row) * DDIM + k0 + chunk * 8;
        const unsigned short* gb = xb + (size_t)(j0 + row) * DDIM + k0 + chunk * 8;
        unsigned short* la = sA + (size_t)row * 64 + schunk * 8;
        unsigned short* lb = sB + (size_t)row * 64 + schunk * 8;
        __builtin_amdgcn_global_load_lds((glob_byte*)ga, (lds_byte*)la, 16, 0, 0);
        __builtin_amdgcn_global_load_lds((glob_byte*)gb, (lds_byte*)lb, 16, 0, 0);
      }
      __syncthreads();   // drain: tile staged (also covers lgmin/sgr init)
#pragma unroll
      for (int ks = 0; ks < 2; ++ks) {
        bf16x8 af[4], bfr[4];
#pragma unroll
        for (int m = 0; m < 4; ++m) {
          int row = wr * 64 + m * 16 + lr;
          int byteoff = row * 128 + ((lh * 16 + ks * 64) ^ ((row & 7) << 4));
          af[m] = *reinterpret_cast<const bf16x8*>(
              reinterpret_cast<const char*>(sA) + byteoff);
        }
#pragma unroll
        for (int n = 0; n < 4; ++n) {
          int row = wc * 64 + n * 16 + lr;
          int byteoff = row * 128 + ((lh * 16 + ks * 64) ^ ((row & 7) << 4));
          bfr[n] = *reinterpret_cast<const bf16x8*>(
              reinterpret_cast<const char*>(sB) + byteoff);
        }
#pragma unroll
        for (int m = 0; m < 4; ++m)
#pragma unroll
          for (int n = 0; n < 4; ++n)
            acc[m][n] = __builtin_amdgcn_mfma_f32_16x16x32_bf16(af[m], bfr[n],
                                                                acc[m][n], 0, 0, 0);
      }
      __syncthreads();   // all waves done reading before next stage overwrites
    }

    // ---------------- fused epilogue ----------------
    // C/D layout: col = lane&15, row = (lane>>4)*4 + reg
    int gi[4][4];
#pragma unroll
    for (int m = 0; m < 4; ++m)
#pragma unroll
      for (int r = 0; r < 4; ++r) gi[m][r] = sgr[wr * 64 + m * 16 + lh * 4 + r];
    int gj[4];
#pragma unroll
    for (int n = 0; n < 4; ++n) gj[n] = sgc[wc * 64 + n * 16 + lr];

    float rmin[4][4], rmax[4][4], cmax[4];
#pragma unroll
    for (int m = 0; m < 4; ++m)
#pragma unroll
      for (int r = 0; r < 4; ++r) { rmin[m][r] = 3.0e38f; rmax[m][r] = -3.0e38f; }
#pragma unroll
    for (int n = 0; n < 4; ++n) cmax[n] = -3.0e38f;

    const bool offdiag = (ib != jb);
#pragma unroll
    for (int m = 0; m < 4; ++m) {
#pragma unroll
      for (int r = 0; r < 4; ++r) {
        int ii = i0 + wr * 64 + m * 16 + lh * 4 + r;
#pragma unroll
        for (int n = 0; n < 4; ++n) {
          int jj = j0 + wc * 64 + n * 16 + lr;
          float s = acc[m][n][r];
          if (offdiag || (ii > jj)) {
            if (gi[m][r] == gj[n]) {
              rmin[m][r] = fminf(rmin[m][r], s);
            } else {
              rmax[m][r] = fmaxf(rmax[m][r], s);
              cmax[n] = fmaxf(cmax[n], s);
            }
          }
        }
      }
    }

    // reduce rows across the 16 j-lanes (xor 1,2,4,8)
#pragma unroll
    for (int s = 1; s <= 8; s <<= 1) {
#pragma unroll
      for (int m = 0; m < 4; ++m)
#pragma unroll
        for (int r = 0; r < 4; ++r) {
          rmin[m][r] = fminf(rmin[m][r], __shfl_xor(rmin[m][r], s, 64));
          rmax[m][r] = fmaxf(rmax[m][r], __shfl_xor(rmax[m][r], s, 64));
        }
    }
    // reduce cols across the 4 i-lane-groups (xor 16, 32)
#pragma unroll
    for (int s = 16; s <= 32; s <<= 1)
#pragma unroll
      for (int n = 0; n < 4; ++n)
        cmax[n] = fmaxf(cmax[n], __shfl_xor(cmax[n], s, 64));

    if (lr == 0) {
#pragma unroll
      for (int m = 0; m < 4; ++m)
#pragma unroll
        for (int r = 0; r < 4; ++r) {
          if (rmin[m][r] < 1.0e38f) atomicMin(&lgmin[gi[m][r]], enc_f32(rmin[m][r]));
          if (rmax[m][r] > -1.0e38f) atomicMax(&lgmax[gi[m][r]], enc_f32(rmax[m][r]));
        }
    }
    if (lh == 0) {
#pragma unroll
      for (int n = 0; n < 4; ++n)
        if (cmax[n] > -1.0e38f) atomicMax(&lgmax[gj[n]], enc_f32(cmax[n]));
    }
    __syncthreads();

    if (tid < NUMG) {
      uint32_t mn = lgmin[tid], mx = lgmax[tid];
      if (mn != 0xFFFFFFFFu) atomicMin(&gmin[tid], mn);
      if (mx != 0u) atomicMax(&gmax[tid], mx);
    }
    __syncthreads();   // merge reads done before next tile re-inits lgmin
  }
}

// ---------------- finalize: per-group margin + mean ----------------
__global__ void finalize_k(const uint32_t* __restrict__ gmin,
                           const uint32_t* __restrict__ gmax,
                           const int* __restrict__ counts,
                           float* __restrict__ out) {
  __shared__ float s_num[256];
  __shared__ float s_den[256];
  int t = threadIdx.x;
  float per = 0.f, ne = 0.f;
  if (counts[t] > 0) {
    ne = 1.f;
    float mn = (gmin[t] == 0xFFFFFFFFu) ? 1.0e9f : dec_f32(gmin[t]);
    float mx = (gmax[t] == 0u) ? -1.0e9f : dec_f32(gmax[t]);
    per = fmaxf(0.0f, mx - mn + MARGIN_F);
  }
  s_num[t] = per;
  s_den[t] = ne;
  __syncthreads();
  for (int s = 128; s > 0; s >>= 1) {
    if (t < s) { s_num[t] += s_num[t + s]; s_den[t] += s_den[t + s]; }
    __syncthreads();
  }
  if (t == 0) out[0] = s_num[0] / s_den[0];
}

extern "C" void kernel_launch(void* const* d_in, const int* in_sizes, int n_in,
                              void* d_out, int out_size, void* d_ws, size_t ws_size,
                              hipStream_t stream) {
  const float* x   = (const float*)d_in[0];
  const int* pidx  = (const int*)d_in[1];
  float* out       = (float*)d_out;

  char* ws = (char*)d_ws;
  unsigned short* xb = (unsigned short*)ws;
  size_t off = (size_t)KROWS * DDIM * 2;          // 12,582,912 B
  int* gids      = (int*)(ws + off); off += (size_t)KROWS * 4;
  uint32_t* gmin = (uint32_t*)(ws + off); off += NUMG * 4;
  uint32_t* gmax = (uint32_t*)(ws + off); off += NUMG * 4;   // gmax, counts adjacent
  int* counts    = (int*)(ws + off); off += NUMG * 4;
  int* ctr       = (int*)(ws + off); off += 4;

  // init: gmin = 0xFFFFFFFF (encodes +max), gmax = 0 (encodes -max), counts = 0
  hipMemsetAsync(gmin, 0xFF, NUMG * 4, stream);
  hipMemsetAsync(gmax, 0x00, NUMG * 8, stream);   // covers gmax + counts

  hipLaunchKernelGGL(convert_k, dim3((KROWS * DDIM / 8) / 256), dim3(256), 0, stream,
                     x, xb, pidx, gids, counts, ctr);
  hipLaunchKernelGGL(gram_margin_k, dim3(GRID_G), dim3(1024), 0,
                     stream, xb, gids, gmin, gmax, ctr);
  hipLaunchKernelGGL(finalize_k, dim3(1), dim3(NUMG), 0, stream,
                     gmin, gmax, counts, out);
}

// Round 7
// 118.912 us; speedup vs baseline: 1.0826x; 1.0826x over previous
//
#include <hip/hip_runtime.h>
#include <stdint.h>

#define KROWS 8192
#define DDIM  768
#define NUMG  256
#define BM    128
#define BK    64
#define NT    (DDIM / BK)                 // 12 K-tiles
#define NTILES (KROWS / BM)               // 64
#define TOTT (NTILES * (NTILES + 1) / 2)  // 2080
#define GRID_G 1024                       // = 256 CUs x 4 blocks/CU (reg-limited)
#define MARGIN_F 0.1f

typedef short bf16x8 __attribute__((ext_vector_type(8)));
typedef float f32x4 __attribute__((ext_vector_type(4)));
typedef unsigned short u16x8 __attribute__((ext_vector_type(8)));

typedef __attribute__((address_space(3))) unsigned char lds_byte;
typedef __attribute__((address_space(1))) const unsigned char glob_byte;

__device__ __forceinline__ uint32_t enc_f32(float f) {
  uint32_t b = __float_as_uint(f);
  return (b & 0x80000000u) ? ~b : (b | 0x80000000u);
}
__device__ __forceinline__ float dec_f32(uint32_t u) {
  uint32_t b = (u & 0x80000000u) ? (u & 0x7FFFFFFFu) : ~u;
  return __uint_as_float(b);
}
__device__ __forceinline__ unsigned short f2bf(float f) {
  uint32_t b = __float_as_uint(f);
  uint32_t r = (b + 0x7FFFu + ((b >> 16) & 1u)) >> 16;
  return (unsigned short)r;
}

// ------- convert f32->bf16 (8/thread) + gid extract + steal-counter init ----
__global__ void convert_k(const float* __restrict__ x, unsigned short* __restrict__ xb,
                          const int* __restrict__ pidx, int* __restrict__ gids,
                          int* __restrict__ counts, int* __restrict__ ctr) {
  int t = blockIdx.x * blockDim.x + threadIdx.x;
  const float4* p = reinterpret_cast<const float4*>(x + 8 * (size_t)t);
  float4 a = p[0], b = p[1];
  u16x8 r;
  r[0] = f2bf(a.x); r[1] = f2bf(a.y); r[2] = f2bf(a.z); r[3] = f2bf(a.w);
  r[4] = f2bf(b.x); r[5] = f2bf(b.y); r[6] = f2bf(b.z); r[7] = f2bf(b.w);
  *reinterpret_cast<u16x8*>(xb + 8 * (size_t)t) = r;
  if (t < KROWS) {
    int g = pidx[2 * t + 1] & (NUMG - 1);
    gids[t] = g;
    atomicAdd(&counts[g], 1);
  }
  if (t == 0) *ctr = GRID_G;  // stealing starts after the static first tile/block
}

// ---------------- main fused Gram + margin-reduce kernel ----------------
// r5 structure verbatim (128x128 tile, 4 waves 2x2, single-buffer serial-drain
// K-loop, XOR-swizzled LDS via pre-swizzled global source, fused min/max
// epilogue) + PERSISTENT WORK-STEALING: 1024 blocks (exactly the 4-blocks/CU
// residency) each grab tiles from an atomic counter. Removes the 3-round
// makespan quantization of a 2080-block launch (2080/1024 = 2.03 -> ceil 3).
// Tile order: supertile-contiguous (8x8-tile supertiles, diag first).
// Min/max atomics are order-independent -> deterministic output.
__launch_bounds__(256, 2)
__global__ void gram_margin_k(const unsigned short* __restrict__ xb,
                              const int* __restrict__ gids,
                              uint32_t* __restrict__ gmin,
                              uint32_t* __restrict__ gmax,
                              int* __restrict__ ctr) {
  __shared__ unsigned short sA[BM * BK];
  __shared__ unsigned short sB[BM * BK];
  __shared__ uint32_t lgmin[NUMG];
  __shared__ uint32_t lgmax[NUMG];
  __shared__ int sgr[BM];
  __shared__ int sgc[BM];
  __shared__ int s_tile;

  const int tid  = threadIdx.x;
  const int lane = tid & 63;
  const int wid  = tid >> 6;
  const int wr   = wid >> 1, wc = wid & 1;
  const int lr   = lane & 15, lh = lane >> 4;
  const int srow = tid >> 3;   // 0..31 (row within 32-row staging chunk)
  const int schunk = tid & 7;  // 16B chunk within 128B row

  bool first = true;
  for (;;) {
    if (tid == 0) s_tile = first ? (int)blockIdx.x : atomicAdd(ctr, 1);
    __syncthreads();
    first = false;
    const int idx = s_tile;
    if (idx >= TOTT) break;

    // supertile-contiguous decode: idx 0..287 = 8 diagonal 8x8 supertiles
    // (36 tiles each); idx 288..2079 = 28 off-diag supertiles (64 tiles each).
    int ib, jb;
    if (idx < 288) {
      int d = idx / 36, r = idx - d * 36;
      int i2 = (int)((sqrtf(8.0f * (float)r + 1.0f) - 1.0f) * 0.5f);
      while ((i2 + 1) * (i2 + 2) / 2 <= r) ++i2;
      while (i2 * (i2 + 1) / 2 > r) --i2;
      int j2 = r - i2 * (i2 + 1) / 2;
      ib = d * 8 + i2; jb = d * 8 + j2;
    } else {
      int o = (idx - 288) >> 6, t2 = (idx - 288) & 63;
      int si = (int)((sqrtf(8.0f * (float)o + 1.0f) - 1.0f) * 0.5f);
      while ((si + 1) * (si + 2) / 2 <= o) ++si;
      while (si * (si + 1) / 2 > o) --si;
      int sj = o - si * (si + 1) / 2;
      si += 1;                       // strictly-lower supertile: SI in 1..7
      ib = si * 8 + (t2 >> 3); jb = sj * 8 + (t2 & 7);
    }
    const int i0 = ib * BM, j0 = jb * BM;

    if (tid < NUMG) { lgmin[tid] = 0xFFFFFFFFu; lgmax[tid] = 0u; }
    if (tid < BM)   { sgr[tid] = gids[i0 + tid]; sgc[tid] = gids[j0 + tid]; }

    f32x4 acc[4][4];
    const f32x4 zz = {0.f, 0.f, 0.f, 0.f};
#pragma unroll
    for (int m = 0; m < 4; ++m)
#pragma unroll
      for (int n = 0; n < 4; ++n) acc[m][n] = zz;

    for (int kt = 0; kt < NT; ++kt) {
      const int k0 = kt * BK;
#pragma unroll
      for (int c = 0; c < 4; ++c) {
        int row = c * 32 + srow;
        int chunk = schunk ^ (row & 7);  // pre-swizzle global source
        const unsigned short* ga = xb + (size_t)(i0 + row) * DDIM + k0 + chunk * 8;
        const unsigned short* gb = xb + (size_t)(j0 + row) * DDIM + k0 + chunk * 8;
        unsigned short* la = sA + c * 2048 + tid * 8;
        unsigned short* lb = sB + c * 2048 + tid * 8;
        __builtin_amdgcn_global_load_lds((glob_byte*)ga, (lds_byte*)la, 16, 0, 0);
        __builtin_amdgcn_global_load_lds((glob_byte*)gb, (lds_byte*)lb, 16, 0, 0);
      }
      __syncthreads();   // drain: tile staged (also covers lgmin/sgr init)
#pragma unroll
      for (int ks = 0; ks < 2; ++ks) {
        bf16x8 af[4], bfr[4];
#pragma unroll
        for (int m = 0; m < 4; ++m) {
          int row = wr * 64 + m * 16 + lr;
          int byteoff = row * 128 + ((lh * 16 + ks * 64) ^ ((row & 7) << 4));
          af[m] = *reinterpret_cast<const bf16x8*>(
              reinterpret_cast<const char*>(sA) + byteoff);
        }
#pragma unroll
        for (int n = 0; n < 4; ++n) {
          int row = wc * 64 + n * 16 + lr;
          int byteoff = row * 128 + ((lh * 16 + ks * 64) ^ ((row & 7) << 4));
          bfr[n] = *reinterpret_cast<const bf16x8*>(
              reinterpret_cast<const char*>(sB) + byteoff);
        }
#pragma unroll
        for (int m = 0; m < 4; ++m)
#pragma unroll
          for (int n = 0; n < 4; ++n)
            acc[m][n] = __builtin_amdgcn_mfma_f32_16x16x32_bf16(af[m], bfr[n],
                                                                acc[m][n], 0, 0, 0);
      }
      __syncthreads();   // all waves done reading before next stage overwrites
    }

    // ---------------- fused epilogue ----------------
    // C/D layout: col = lane&15, row = (lane>>4)*4 + reg
    int gi[4][4];
#pragma unroll
    for (int m = 0; m < 4; ++m)
#pragma unroll
      for (int r = 0; r < 4; ++r) gi[m][r] = sgr[wr * 64 + m * 16 + lh * 4 + r];
    int gj[4];
#pragma unroll
    for (int n = 0; n < 4; ++n) gj[n] = sgc[wc * 64 + n * 16 + lr];

    float rmin[4][4], rmax[4][4], cmax[4];
#pragma unroll
    for (int m = 0; m < 4; ++m)
#pragma unroll
      for (int r = 0; r < 4; ++r) { rmin[m][r] = 3.0e38f; rmax[m][r] = -3.0e38f; }
#pragma unroll
    for (int n = 0; n < 4; ++n) cmax[n] = -3.0e38f;

    const bool offdiag = (ib != jb);
#pragma unroll
    for (int m = 0; m < 4; ++m) {
#pragma unroll
      for (int r = 0; r < 4; ++r) {
        int ii = i0 + wr * 64 + m * 16 + lh * 4 + r;
#pragma unroll
        for (int n = 0; n < 4; ++n) {
          int jj = j0 + wc * 64 + n * 16 + lr;
          float s = acc[m][n][r];
          if (offdiag || (ii > jj)) {
            if (gi[m][r] == gj[n]) {
              rmin[m][r] = fminf(rmin[m][r], s);
            } else {
              rmax[m][r] = fmaxf(rmax[m][r], s);
              cmax[n] = fmaxf(cmax[n], s);
            }
          }
        }
      }
    }

    // reduce rows across the 16 j-lanes (xor 1,2,4,8)
#pragma unroll
    for (int s = 1; s <= 8; s <<= 1) {
#pragma unroll
      for (int m = 0; m < 4; ++m)
#pragma unroll
        for (int r = 0; r < 4; ++r) {
          rmin[m][r] = fminf(rmin[m][r], __shfl_xor(rmin[m][r], s, 64));
          rmax[m][r] = fmaxf(rmax[m][r], __shfl_xor(rmax[m][r], s, 64));
        }
    }
    // reduce cols across the 4 i-lane-groups (xor 16, 32)
#pragma unroll
    for (int s = 16; s <= 32; s <<= 1)
#pragma unroll
      for (int n = 0; n < 4; ++n)
        cmax[n] = fmaxf(cmax[n], __shfl_xor(cmax[n], s, 64));

    if (lr == 0) {
#pragma unroll
      for (int m = 0; m < 4; ++m)
#pragma unroll
        for (int r = 0; r < 4; ++r) {
          if (rmin[m][r] < 1.0e38f) atomicMin(&lgmin[gi[m][r]], enc_f32(rmin[m][r]));
          if (rmax[m][r] > -1.0e38f) atomicMax(&lgmax[gi[m][r]], enc_f32(rmax[m][r]));
        }
    }
    if (lh == 0) {
#pragma unroll
      for (int n = 0; n < 4; ++n)
        if (cmax[n] > -1.0e38f) atomicMax(&lgmax[gj[n]], enc_f32(cmax[n]));
    }
    __syncthreads();

    if (tid < NUMG) {
      uint32_t mn = lgmin[tid], mx = lgmax[tid];
      if (mn != 0xFFFFFFFFu) atomicMin(&gmin[tid], mn);
      if (mx != 0u) atomicMax(&gmax[tid], mx);
    }
    __syncthreads();   // merge reads done before next tile re-inits lgmin/s_tile
  }
}

// ---------------- finalize: per-group margin + mean ----------------
__global__ void finalize_k(const uint32_t* __restrict__ gmin,
                           const uint32_t* __restrict__ gmax,
                           const int* __restrict__ counts,
                           float* __restrict__ out) {
  __shared__ float s_num[256];
  __shared__ float s_den[256];
  int t = threadIdx.x;
  float per = 0.f, ne = 0.f;
  if (counts[t] > 0) {
    ne = 1.f;
    float mn = (gmin[t] == 0xFFFFFFFFu) ? 1.0e9f : dec_f32(gmin[t]);
    float mx = (gmax[t] == 0u) ? -1.0e9f : dec_f32(gmax[t]);
    per = fmaxf(0.0f, mx - mn + MARGIN_F);
  }
  s_num[t] = per;
  s_den[t] = ne;
  __syncthreads();
  for (int s = 128; s > 0; s >>= 1) {
    if (t < s) { s_num[t] += s_num[t + s]; s_den[t] += s_den[t + s]; }
    __syncthreads();
  }
  if (t == 0) out[0] = s_num[0] / s_den[0];
}

extern "C" void kernel_launch(void* const* d_in, const int* in_sizes, int n_in,
                              void* d_out, int out_size, void* d_ws, size_t ws_size,
                              hipStream_t stream) {
  const float* x   = (const float*)d_in[0];
  const int* pidx  = (const int*)d_in[1];
  float* out       = (float*)d_out;

  char* ws = (char*)d_ws;
  unsigned short* xb = (unsigned short*)ws;
  size_t off = (size_t)KROWS * DDIM * 2;          // 12,582,912 B
  int* gids      = (int*)(ws + off); off += (size_t)KROWS * 4;
  uint32_t* gmin = (uint32_t*)(ws + off); off += NUMG * 4;
  uint32_t* gmax = (uint32_t*)(ws + off); off += NUMG * 4;   // gmax, counts adjacent
  int* counts    = (int*)(ws + off); off += NUMG * 4;
  int* ctr       = (int*)(ws + off); off += 4;

  // init: gmin = 0xFFFFFFFF (encodes +max), gmax = 0 (encodes -max), counts = 0
  hipMemsetAsync(gmin, 0xFF, NUMG * 4, stream);
  hipMemsetAsync(gmax, 0x00, NUMG * 8, stream);   // covers gmax + counts

  hipLaunchKernelGGL(convert_k, dim3((KROWS * DDIM / 8) / 256), dim3(256), 0, stream,
                     x, xb, pidx, gids, counts, ctr);
  hipLaunchKernelGGL(gram_margin_k, dim3(GRID_G), dim3(256), 0,
                     stream, xb, gids, gmin, gmax, ctr);
  hipLaunchKernelGGL(finalize_k, dim3(1), dim3(NUMG), 0, stream,
                     gmin, gmax, counts, out);
}